// Round 3
// baseline (13414.482 us; speedup 1.0000x reference)
//
#include <hip/hip_runtime.h>
#include <hip/hip_bf16.h>

typedef __hip_bfloat16 bf16;
typedef short s8v __attribute__((ext_vector_type(8)));   // 8 bf16 payload for MFMA
typedef float f4v __attribute__((ext_vector_type(4)));   // MFMA accumulator

#define B_   32
#define L_   64
#define TENC 196
#define INP  2048
#define H_   512
#define V_   32000

static __device__ __forceinline__ float sigf(float x) { return 1.0f / (1.0f + expf(-x)); }
static __device__ __forceinline__ void split_hl(float v, bf16& hi, bf16& lo) {
    hi = (bf16)v;
    lo = (bf16)(v - (float)hi);
}
static __device__ __forceinline__ short f2bs(float x) {
    bf16 h = (bf16)x;
    return *(short*)&h;
}
// scalar load of logical element i from a float-typed input (f32 or bf16 storage)
static __device__ __forceinline__ float ldf(const void* p, size_t i, int f32) {
    if (f32) return ((const float*)p)[i];
    return (float)((const bf16*)p)[i];
}
// 8 consecutive logical elements -> 8 bf16 (rounded if f32 storage). i must be 8-aligned.
static __device__ __forceinline__ s8v ld8(const void* p, size_t i, int f32) {
    if (f32) {
        const float* fp = (const float*)p + i;
        float4 a = *(const float4*)fp;
        float4 b = *(const float4*)(fp + 4);
        s8v r;
        r[0] = f2bs(a.x); r[1] = f2bs(a.y); r[2] = f2bs(a.z); r[3] = f2bs(a.w);
        r[4] = f2bs(b.x); r[5] = f2bs(b.y); r[6] = f2bs(b.z); r[7] = f2bs(b.w);
        return r;
    }
    return *(const s8v*)((const bf16*)p + i);
}
// lo-residual of 8 elements (zero if storage is bf16 = exact)
static __device__ __forceinline__ s8v ld8lo(const void* p, size_t i, int f32) {
    s8v r = {};
    if (f32) {
        const float* fp = (const float*)p + i;
        float4 a = *(const float4*)fp;
        float4 b = *(const float4*)(fp + 4);
        float v[8] = {a.x, a.y, a.z, a.w, b.x, b.y, b.z, b.w};
        for (int j = 0; j < 8; ++j) {
            bf16 hi = (bf16)v[j];
            bf16 lo = (bf16)(v[j] - (float)hi);
            r[j] = *(short*)&lo;
        }
    }
    return r;
}

// ---------------- dtype detector: bf16-interpret features; huge magnitudes => f32 ----
__global__ __launch_bounds__(256) void k_detect(const void* __restrict__ feat,
                                                int* __restrict__ flag) {
    __shared__ float red[256];
    const unsigned short* p = (const unsigned short*)feat;
    float mx = 0.f;
    for (int i = threadIdx.x; i < 65536; i += 256) {
        unsigned int u = ((unsigned int)p[i]) << 16;
        float v = __uint_as_float(u);
        float av = fabsf(v);
        mx = fmaxf(mx, av);   // NaN inputs dropped by IEEE maxNum; huge finites abound if f32
    }
    red[threadIdx.x] = mx;
    __syncthreads();
    for (int s = 128; s; s >>= 1) {
        if (threadIdx.x < s) red[threadIdx.x] = fmaxf(red[threadIdx.x], red[threadIdx.x + s]);
        __syncthreads();
    }
    if (threadIdx.x == 0) flag[0] = (red[0] > 1e4f) ? 1 : 0;
}

// ---------------- feature MLP: t1 = relu(features @ ft1_w.T + b1) ----------------
__global__ __launch_bounds__(256) void k_feat1(const int* __restrict__ dflag,
                                               const void* __restrict__ feat,
                                               const void* __restrict__ w,
                                               const void* __restrict__ bias,
                                               float* __restrict__ t1) {
    int f32 = *dflag;
    int wid = (blockIdx.x * 256 + threadIdx.x) >> 6;   // 16384 waves, 1 output each
    int lane = threadIdx.x & 63;
    int b = wid >> 9, o = wid & 511;
    float acc = 0.f;
    for (int k = lane; k < INP; k += 64)
        acc += ldf(feat, (size_t)b * INP + k, f32) * ldf(w, (size_t)o * INP + k, f32);
    for (int off = 32; off; off >>= 1) acc += __shfl_down(acc, off, 64);
    if (lane == 0) {
        acc += ldf(bias, o, f32);
        t1[b * H_ + o] = acc > 0.f ? acc : 0.f;
    }
}

// f = t1 @ ft2_w.T + b2 ; init h0=c0=h1=c1=f (hi/lo bf16 for h, f32 for c)
__global__ __launch_bounds__(256) void k_feat2(const int* __restrict__ dflag,
                                               const float* __restrict__ t1,
                                               const void* __restrict__ w,
                                               const void* __restrict__ bias,
                                               float* __restrict__ c0, float* __restrict__ c1,
                                               bf16* __restrict__ h0hi, bf16* __restrict__ h0lo,
                                               bf16* __restrict__ h1hi, bf16* __restrict__ h1lo) {
    int f32 = *dflag;
    int wid = (blockIdx.x * 256 + threadIdx.x) >> 6;
    int lane = threadIdx.x & 63;
    int b = wid >> 9, o = wid & 511;
    float acc = 0.f;
    for (int k = lane; k < H_; k += 64)
        acc += t1[b * H_ + k] * ldf(w, (size_t)o * H_ + k, f32);
    for (int off = 32; off; off >>= 1) acc += __shfl_down(acc, off, 64);
    if (lane == 0) {
        float v = acc + ldf(bias, o, f32);
        int idx = b * H_ + o;
        c0[idx] = v; c1[idx] = v;
        bf16 hi, lo; split_hl(v, hi, lo);
        h0hi[idx] = hi; h0lo[idx] = lo;
        h1hi[idx] = hi; h1lo[idx] = lo;
    }
}

// ---------------- attention: ctx = softmax(h1 . enc^T * SCALE) @ enc ----------------
__global__ __launch_bounds__(256) void k_att(const int* __restrict__ dflag,
                                             const void* __restrict__ enc,
                                             const bf16* __restrict__ h1hi,
                                             const bf16* __restrict__ h1lo,
                                             bf16* __restrict__ ctxhi, bf16* __restrict__ ctxlo) {
    __shared__ float qs[H_];
    __shared__ float sc[256];
    __shared__ float red[256];
    const float SCALE = 0.04419417382415922f;  // 1/sqrt(512)
    int f32 = *dflag;
    int b = blockIdx.x, tid = threadIdx.x;
    int lane = tid & 63, wv = tid >> 6;
    for (int i = tid; i < H_; i += 256)
        qs[i] = (float)h1hi[b * H_ + i] + (float)h1lo[b * H_ + i];
    __syncthreads();
    // scores: wave per t-row
    for (int t = wv; t < TENC; t += 4) {
        size_t base = ((size_t)b * TENC + t) * H_;
        float a = 0.f;
        for (int k = lane; k < H_; k += 64) a += qs[k] * ldf(enc, base + k, f32);
        for (int off = 32; off; off >>= 1) a += __shfl_down(a, off, 64);
        if (lane == 0) sc[t] = a * SCALE;
    }
    __syncthreads();
    // softmax over 196
    red[tid] = (tid < TENC) ? sc[tid] : -1e30f;
    __syncthreads();
    for (int s = 128; s; s >>= 1) { if (tid < s) red[tid] = fmaxf(red[tid], red[tid + s]); __syncthreads(); }
    float m = red[0];
    __syncthreads();
    float e = (tid < TENC) ? expf(sc[tid] - m) : 0.f;
    red[tid] = e;
    __syncthreads();
    for (int s = 128; s; s >>= 1) { if (tid < s) red[tid] += red[tid + s]; __syncthreads(); }
    float inv = 1.0f / red[0];
    __syncthreads();
    if (tid < TENC) sc[tid] = e * inv;
    __syncthreads();
    // ctx: thread owns 2 adjacent j columns
    int j0 = tid * 2;
    float a0 = 0.f, a1 = 0.f;
    for (int t = 0; t < TENC; ++t) {
        size_t base = ((size_t)b * TENC + t) * H_ + j0;
        float p = sc[t];
        a0 += p * ldf(enc, base, f32);
        a1 += p * ldf(enc, base + 1, f32);
    }
    bf16 hi, lo;
    split_hl(a0, hi, lo); ctxhi[b * H_ + j0] = hi; ctxlo[b * H_ + j0] = lo;
    split_hl(a1, hi, lo); ctxhi[b * H_ + j0 + 1] = hi; ctxlo[b * H_ + j0 + 1] = lo;
}

// ---------------- LSTM cell 0: x=[emb,ctx], K=1536 ; 64 blocks x 8 hidden units -----
__global__ __launch_bounds__(256) void k_cell0(const int* __restrict__ dflag,
                                               const int* __restrict__ captions, int tstep,
                                               const void* __restrict__ embed,
                                               const bf16* __restrict__ ctxhi, const bf16* __restrict__ ctxlo,
                                               const bf16* __restrict__ h0hi_p, const bf16* __restrict__ h0lo_p,
                                               bf16* __restrict__ h0hi_n, bf16* __restrict__ h0lo_n,
                                               float* __restrict__ c0,
                                               const void* __restrict__ w_ih, const void* __restrict__ w_hh,
                                               const void* __restrict__ b_ih, const void* __restrict__ b_hh) {
    __shared__ short Asm[64][136];   // 128 k-cols + 8 pad
    __shared__ short Wsm[32][136];
    __shared__ float ep[4][8][32];
    int f32 = *dflag;
    int u0 = blockIdx.x * 8;
    int tid = threadIdx.x, lane = tid & 63, wv = tid >> 6;
    f4v acc0 = {}, acc1 = {};
    for (int kc = 0; kc < 12; ++kc) {
        int kbase = kc * 128;
        // A: 64 rows (2*batch+part) x 16 segs of 8
        for (int s = tid; s < 1024; s += 256) {
            int r = s >> 4, cseg = (s & 15) * 8;
            int b = r >> 1, part = r & 1;
            int k = kbase + cseg;
            s8v val;
            if (k < 512) {
                size_t ei = (size_t)captions[b * L_ + tstep] * H_ + k;
                val = part ? ld8lo(embed, ei, f32) : ld8(embed, ei, f32);
            } else if (k < 1024) {
                const bf16* src = (part ? ctxlo : ctxhi) + b * H_ + (k - 512);
                val = *(const s8v*)src;
            } else {
                const bf16* src = (part ? h0lo_p : h0hi_p) + b * H_ + (k - 1024);
                val = *(const s8v*)src;
            }
            *(s8v*)&Asm[r][cseg] = val;
        }
        // W: 32 rows ({i,f,g,o} x 8 units) x 16 segs
        for (int s = tid; s < 512; s += 256) {
            int ri = s >> 4, cseg = (s & 15) * 8;
            int k = kbase + cseg;
            int gate = ri >> 3, unit = u0 + (ri & 7);
            size_t j = (size_t)(gate * H_ + unit);
            s8v wv8 = (k < 1024) ? ld8(w_ih, j * 1024 + k, f32)
                                 : ld8(w_hh, j * 512 + (k - 1024), f32);
            *(s8v*)&Wsm[ri][cseg] = wv8;
        }
        __syncthreads();
        int mrow = wv * 16 + (lane & 15);
        for (int kk = 0; kk < 4; ++kk) {
            int kcol = kk * 32 + (lane >> 4) * 8;
            s8v a  = *(const s8v*)&Asm[mrow][kcol];
            s8v b0 = *(const s8v*)&Wsm[lane & 15][kcol];
            s8v b1 = *(const s8v*)&Wsm[16 + (lane & 15)][kcol];
            acc0 = __builtin_amdgcn_mfma_f32_16x16x32_bf16(a, b0, acc0, 0, 0, 0);
            acc1 = __builtin_amdgcn_mfma_f32_16x16x32_bf16(a, b1, acc1, 0, 0, 0);
        }
        __syncthreads();
    }
    // D: col=lane&15 (W row), row=quad*4+reg (A row); regs (2k,2k+1) = (hi,lo) of one batch
    int n = lane & 15, quad = lane >> 4;
    int b0i = wv * 8 + quad * 2;
    ep[n >> 3][n & 7][b0i]     = acc0[0] + acc0[1];
    ep[n >> 3][n & 7][b0i + 1] = acc0[2] + acc0[3];
    ep[2 + (n >> 3)][n & 7][b0i]     = acc1[0] + acc1[1];
    ep[2 + (n >> 3)][n & 7][b0i + 1] = acc1[2] + acc1[3];
    __syncthreads();
    int b = tid & 31, u = tid >> 5;
    int j = u0 + u;
    float gi = ep[0][u][b] + ldf(b_ih, j, f32)        + ldf(b_hh, j, f32);
    float gf = ep[1][u][b] + ldf(b_ih, 512 + j, f32)  + ldf(b_hh, 512 + j, f32);
    float gg = ep[2][u][b] + ldf(b_ih, 1024 + j, f32) + ldf(b_hh, 1024 + j, f32);
    float go = ep[3][u][b] + ldf(b_ih, 1536 + j, f32) + ldf(b_hh, 1536 + j, f32);
    float c = c0[b * H_ + j];
    float c2 = sigf(gf) * c + sigf(gi) * tanhf(gg);
    float h2 = sigf(go) * tanhf(c2);
    c0[b * H_ + j] = c2;
    bf16 hi, lo; split_hl(h2, hi, lo);
    h0hi_n[b * H_ + j] = hi; h0lo_n[b * H_ + j] = lo;
}

// ---------------- LSTM cell 1: x=h0n, K=1024 ; also writes hs row (bf16) ----------
__global__ __launch_bounds__(256) void k_cell1(const int* __restrict__ dflag, int tstep,
                                               const bf16* __restrict__ xhi, const bf16* __restrict__ xlo,
                                               const bf16* __restrict__ h1hi_p, const bf16* __restrict__ h1lo_p,
                                               bf16* __restrict__ h1hi_n, bf16* __restrict__ h1lo_n,
                                               float* __restrict__ c1,
                                               const void* __restrict__ w_ih, const void* __restrict__ w_hh,
                                               const void* __restrict__ b_ih, const void* __restrict__ b_hh,
                                               bf16* __restrict__ hs) {
    __shared__ short Asm[64][136];
    __shared__ short Wsm[32][136];
    __shared__ float ep[4][8][32];
    int f32 = *dflag;
    int u0 = blockIdx.x * 8;
    int tid = threadIdx.x, lane = tid & 63, wv = tid >> 6;
    f4v acc0 = {}, acc1 = {};
    for (int kc = 0; kc < 8; ++kc) {
        int kbase = kc * 128;
        for (int s = tid; s < 1024; s += 256) {
            int r = s >> 4, cseg = (s & 15) * 8;
            int b = r >> 1, part = r & 1;
            int k = kbase + cseg;
            const bf16* src;
            if (k < 512) src = (part ? xlo : xhi) + b * H_ + k;
            else         src = (part ? h1lo_p : h1hi_p) + b * H_ + (k - 512);
            *(s8v*)&Asm[r][cseg] = *(const s8v*)src;
        }
        for (int s = tid; s < 512; s += 256) {
            int ri = s >> 4, cseg = (s & 15) * 8;
            int k = kbase + cseg;
            int gate = ri >> 3, unit = u0 + (ri & 7);
            size_t j = (size_t)(gate * H_ + unit);
            s8v wv8 = (k < 512) ? ld8(w_ih, j * 512 + k, f32)
                                : ld8(w_hh, j * 512 + (k - 512), f32);
            *(s8v*)&Wsm[ri][cseg] = wv8;
        }
        __syncthreads();
        int mrow = wv * 16 + (lane & 15);
        for (int kk = 0; kk < 4; ++kk) {
            int kcol = kk * 32 + (lane >> 4) * 8;
            s8v a  = *(const s8v*)&Asm[mrow][kcol];
            s8v b0 = *(const s8v*)&Wsm[lane & 15][kcol];
            s8v b1 = *(const s8v*)&Wsm[16 + (lane & 15)][kcol];
            acc0 = __builtin_amdgcn_mfma_f32_16x16x32_bf16(a, b0, acc0, 0, 0, 0);
            acc1 = __builtin_amdgcn_mfma_f32_16x16x32_bf16(a, b1, acc1, 0, 0, 0);
        }
        __syncthreads();
    }
    int n = lane & 15, quad = lane >> 4;
    int b0i = wv * 8 + quad * 2;
    ep[n >> 3][n & 7][b0i]     = acc0[0] + acc0[1];
    ep[n >> 3][n & 7][b0i + 1] = acc0[2] + acc0[3];
    ep[2 + (n >> 3)][n & 7][b0i]     = acc1[0] + acc1[1];
    ep[2 + (n >> 3)][n & 7][b0i + 1] = acc1[2] + acc1[3];
    __syncthreads();
    int b = tid & 31, u = tid >> 5;
    int j = u0 + u;
    float gi = ep[0][u][b] + ldf(b_ih, j, f32)        + ldf(b_hh, j, f32);
    float gf = ep[1][u][b] + ldf(b_ih, 512 + j, f32)  + ldf(b_hh, 512 + j, f32);
    float gg = ep[2][u][b] + ldf(b_ih, 1024 + j, f32) + ldf(b_hh, 1024 + j, f32);
    float go = ep[3][u][b] + ldf(b_ih, 1536 + j, f32) + ldf(b_hh, 1536 + j, f32);
    float c = c1[b * H_ + j];
    float c2 = sigf(gf) * c + sigf(gi) * tanhf(gg);
    float h2 = sigf(go) * tanhf(c2);
    c1[b * H_ + j] = c2;
    bf16 hi, lo; split_hl(h2, hi, lo);
    h1hi_n[b * H_ + j] = hi; h1lo_n[b * H_ + j] = lo;
    hs[((size_t)tstep * B_ + b) * H_ + j] = hi;
}

// ---------------- vocab projection: [2048 x 512] @ fc_w[32000 x 512]^T + fc_b ------
__global__ __launch_bounds__(256) void k_vocab(const int* __restrict__ dflag,
                                               const bf16* __restrict__ hs,
                                               const void* __restrict__ fcw,
                                               const void* __restrict__ fcb,
                                               void* __restrict__ out) {
    __shared__ short As[128][40];   // 32 k-cols + 8 pad
    __shared__ short Bs[128][40];
    int f32 = *dflag;
    int n0 = blockIdx.x * 128;      // 250
    int m0 = blockIdx.y * 128;      // 16
    int tid = threadIdx.x, lane = tid & 63, wv = tid >> 6;
    int wm = wv >> 1, wn = wv & 1;
    f4v acc[16] = {};
    for (int k0 = 0; k0 < 512; k0 += 32) {
        for (int s = tid; s < 512; s += 256) {
            int r = s >> 2, cs = (s & 3) * 8;
            *(s8v*)&As[r][cs] = *(const s8v*)(hs + (size_t)(m0 + r) * 512 + k0 + cs);
        }
        for (int s = tid; s < 512; s += 256) {
            int r = s >> 2, cs = (s & 3) * 8;
            *(s8v*)&Bs[r][cs] = ld8(fcw, (size_t)(n0 + r) * 512 + k0 + cs, f32);
        }
        __syncthreads();
        int kq = (lane >> 4) * 8;
        s8v af[4], bfv[4];
        for (int i = 0; i < 4; ++i) af[i]  = *(const s8v*)&As[wm * 64 + i * 16 + (lane & 15)][kq];
        for (int i = 0; i < 4; ++i) bfv[i] = *(const s8v*)&Bs[wn * 64 + i * 16 + (lane & 15)][kq];
        for (int mi = 0; mi < 4; ++mi)
            for (int ni = 0; ni < 4; ++ni)
                acc[mi * 4 + ni] = __builtin_amdgcn_mfma_f32_16x16x32_bf16(af[mi], bfv[ni], acc[mi * 4 + ni], 0, 0, 0);
        __syncthreads();
    }
    int n = lane & 15, quad = lane >> 4;
    for (int ni = 0; ni < 4; ++ni) {
        int col = n0 + wn * 64 + ni * 16 + n;
        float bias = ldf(fcb, col, f32);
        for (int mi = 0; mi < 4; ++mi) {
            f4v a = acc[mi * 4 + ni];
            for (int rg = 0; rg < 4; ++rg) {
                int row = m0 + wm * 64 + mi * 16 + quad * 4 + rg;
                float v = a[rg] + bias;
                if (f32) ((float*)out)[(size_t)row * V_ + col] = v;
                else     ((bf16*)out)[(size_t)row * V_ + col] = (bf16)v;
            }
        }
    }
}

extern "C" void kernel_launch(void* const* d_in, const int* in_sizes, int n_in,
                              void* d_out, int out_size, void* d_ws, size_t ws_size,
                              hipStream_t stream) {
    const void* features = d_in[0];
    const int*  captions = (const int*)d_in[1];
    // d_in[2] lengths: all == L, unused
    const void* enc      = d_in[3];
    const void* embed    = d_in[4];
    const void* ft1w     = d_in[5];
    const void* ft1b     = d_in[6];
    const void* ft2w     = d_in[7];
    const void* ft2b     = d_in[8];
    const void* w_ih0    = d_in[9];
    const void* w_hh0    = d_in[10];
    const void* b_ih0    = d_in[11];
    const void* b_hh0    = d_in[12];
    const void* w_ih1    = d_in[13];
    const void* w_hh1    = d_in[14];
    const void* b_ih1    = d_in[15];
    const void* b_hh1    = d_in[16];
    const void* fcw      = d_in[17];
    const void* fcb      = d_in[18];

    char* ws = (char*)d_ws;
    size_t off = 0;
    float* t1 = (float*)(ws + off); off += 32 * 512 * 4;
    float* c0 = (float*)(ws + off); off += 32 * 512 * 4;
    float* c1 = (float*)(ws + off); off += 32 * 512 * 4;
    bf16* h0hi[2]; bf16* h0lo[2]; bf16* h1hi[2]; bf16* h1lo[2];
    for (int i = 0; i < 2; ++i) { h0hi[i] = (bf16*)(ws + off); off += 32 * 512 * 2;
                                  h0lo[i] = (bf16*)(ws + off); off += 32 * 512 * 2; }
    for (int i = 0; i < 2; ++i) { h1hi[i] = (bf16*)(ws + off); off += 32 * 512 * 2;
                                  h1lo[i] = (bf16*)(ws + off); off += 32 * 512 * 2; }
    bf16* ctxhi = (bf16*)(ws + off); off += 32 * 512 * 2;
    bf16* ctxlo = (bf16*)(ws + off); off += 32 * 512 * 2;
    bf16* hs = (bf16*)(ws + off); off += (size_t)2048 * 512 * 2;
    int* dflag = (int*)(ws + off); off += 16;

    k_detect<<<1, 256, 0, stream>>>(features, dflag);
    k_feat1<<<4096, 256, 0, stream>>>(dflag, features, ft1w, ft1b, t1);
    k_feat2<<<4096, 256, 0, stream>>>(dflag, t1, ft2w, ft2b, c0, c1,
                                      h0hi[0], h0lo[0], h1hi[0], h1lo[0]);
    for (int t = 0; t < L_; ++t) {
        int p = t & 1, q = p ^ 1;
        k_att<<<32, 256, 0, stream>>>(dflag, enc, h1hi[p], h1lo[p], ctxhi, ctxlo);
        k_cell0<<<64, 256, 0, stream>>>(dflag, captions, t, embed, ctxhi, ctxlo,
                                        h0hi[p], h0lo[p], h0hi[q], h0lo[q], c0,
                                        w_ih0, w_hh0, b_ih0, b_hh0);
        k_cell1<<<64, 256, 0, stream>>>(dflag, t, h0hi[q], h0lo[q], h1hi[p], h1lo[p],
                                        h1hi[q], h1lo[q], c1,
                                        w_ih1, w_hh1, b_ih1, b_hh1, hs);
    }
    k_vocab<<<dim3(250, 16), 256, 0, stream>>>(dflag, hs, fcw, fcb, (void*)d_out);
}

// Round 4
// 7582.632 us; speedup vs baseline: 1.7691x; 1.7691x over previous
//
#include <hip/hip_runtime.h>
#include <hip/hip_bf16.h>

typedef __hip_bfloat16 bf16;
typedef short s8v __attribute__((ext_vector_type(8)));   // 8 bf16 payload for MFMA
typedef float f4v __attribute__((ext_vector_type(4)));   // MFMA accumulator

#define B_   32
#define L_   64
#define TENC 196
#define INP  2048
#define H_   512
#define V_   32000
#define NBLK 128   // persistent-kernel grid (<=256 CUs, 1 block/CU => co-resident)

static __device__ __forceinline__ float sigf(float x) { return 1.0f / (1.0f + expf(-x)); }
static __device__ __forceinline__ void split_hl(float v, bf16& hi, bf16& lo) {
    hi = (bf16)v;
    lo = (bf16)(v - (float)hi);
}
static __device__ __forceinline__ short f2bs(float x) {
    bf16 h = (bf16)x;
    return *(short*)&h;
}
static __device__ __forceinline__ float ldf(const void* p, size_t i, int f32) {
    if (f32) return ((const float*)p)[i];
    return (float)((const bf16*)p)[i];
}
static __device__ __forceinline__ s8v ld8(const void* p, size_t i, int f32) {
    if (f32) {
        const float* fp = (const float*)p + i;
        float4 a = *(const float4*)fp;
        float4 b = *(const float4*)(fp + 4);
        s8v r;
        r[0] = f2bs(a.x); r[1] = f2bs(a.y); r[2] = f2bs(a.z); r[3] = f2bs(a.w);
        r[4] = f2bs(b.x); r[5] = f2bs(b.y); r[6] = f2bs(b.z); r[7] = f2bs(b.w);
        return r;
    }
    return *(const s8v*)((const bf16*)p + i);
}
static __device__ __forceinline__ s8v ld8lo(const void* p, size_t i, int f32) {
    s8v r = {};
    if (f32) {
        const float* fp = (const float*)p + i;
        float4 a = *(const float4*)fp;
        float4 b = *(const float4*)(fp + 4);
        float v[8] = {a.x, a.y, a.z, a.w, b.x, b.y, b.z, b.w};
        for (int j = 0; j < 8; ++j) {
            bf16 hi = (bf16)v[j];
            bf16 lo = (bf16)(v[j] - (float)hi);
            r[j] = *(short*)&lo;
        }
    }
    return r;
}

// device-scope grid barrier (all NBLK blocks co-resident; monotonic counter, no reset)
static __device__ __forceinline__ void gridbar(int* cnt, int target) {
    __syncthreads();
    if (threadIdx.x == 0) {
        __threadfence();   // agent-scope release: L2 writeback (cross-XCD visibility)
        __hip_atomic_fetch_add(cnt, 1, __ATOMIC_RELAXED, __HIP_MEMORY_SCOPE_AGENT);
        while (__hip_atomic_load(cnt, __ATOMIC_RELAXED, __HIP_MEMORY_SCOPE_AGENT) < target)
            __builtin_amdgcn_s_sleep(1);
        __threadfence();   // agent-scope acquire: invalidate stale L1/L2
    }
    __syncthreads();
}

// ---------------- dtype detector ----------------
__global__ __launch_bounds__(256) void k_detect(const void* __restrict__ feat,
                                                int* __restrict__ flag) {
    __shared__ float red[256];
    const unsigned short* p = (const unsigned short*)feat;
    float mx = 0.f;
    for (int i = threadIdx.x; i < 65536; i += 256) {
        unsigned int u = ((unsigned int)p[i]) << 16;
        float v = __uint_as_float(u);
        mx = fmaxf(mx, fabsf(v));
    }
    red[threadIdx.x] = mx;
    __syncthreads();
    for (int s = 128; s; s >>= 1) {
        if (threadIdx.x < s) red[threadIdx.x] = fmaxf(red[threadIdx.x], red[threadIdx.x + s]);
        __syncthreads();
    }
    if (threadIdx.x == 0) flag[0] = (red[0] > 1e4f) ? 1 : 0;
}

// ---------------- pre-convert enc + LSTM weights to bf16; combine biases; init barrier
__global__ __launch_bounds__(256) void k_prep(const int* __restrict__ dflag,
                                              const void* __restrict__ enc,
                                              const void* __restrict__ w_ih0, const void* __restrict__ w_hh0,
                                              const void* __restrict__ w_ih1, const void* __restrict__ w_hh1,
                                              const void* __restrict__ b_ih0, const void* __restrict__ b_hh0,
                                              const void* __restrict__ b_ih1, const void* __restrict__ b_hh1,
                                              bf16* __restrict__ enc16,
                                              bf16* __restrict__ Wp0, bf16* __restrict__ Wp1,
                                              float* __restrict__ bias0, float* __restrict__ bias1,
                                              int* __restrict__ bar) {
    int f32 = *dflag;
    int gid = blockIdx.x * 256 + threadIdx.x;
    if (gid == 0) bar[0] = 0;
    const int GE = (B_ * TENC * H_) / 8;      // 401408
    const int GW = (2048 * 1024) / 8;         // 262144
    int stride = gridDim.x * 256;
    for (int g = gid; g < GE + 2 * GW; g += stride) {
        if (g < GE) {
            *(s8v*)(enc16 + (size_t)g * 8) = ld8(enc, (size_t)g * 8, f32);
        } else if (g < GE + GW) {
            int gg = g - GE; int j = gg >> 7; int k = (gg & 127) * 8;
            s8v v = (k < 512) ? ld8(w_ih0, (size_t)j * 1024 + 512 + k, f32)
                              : ld8(w_hh0, (size_t)j * 512 + (k - 512), f32);
            *(s8v*)(Wp0 + (size_t)j * 1024 + k) = v;
        } else {
            int gg = g - GE - GW; int j = gg >> 7; int k = (gg & 127) * 8;
            s8v v = (k < 512) ? ld8(w_ih1, (size_t)j * 512 + k, f32)
                              : ld8(w_hh1, (size_t)j * 512 + (k - 512), f32);
            *(s8v*)(Wp1 + (size_t)j * 1024 + k) = v;
        }
    }
    for (int j = gid; j < 2048; j += stride) {
        bias0[j] = ldf(b_ih0, j, f32) + ldf(b_hh0, j, f32);
        bias1[j] = ldf(b_ih1, j, f32) + ldf(b_hh1, j, f32);
    }
}

// ---------------- Gemb[t*32+b][j] = emb(hi/lo) @ w_ih0[:, 0:512]^T  (f32 out) --------
__global__ __launch_bounds__(256) void k_gemb(const int* __restrict__ dflag,
                                              const int* __restrict__ captions,
                                              const void* __restrict__ embed,
                                              const void* __restrict__ w_ih0,
                                              float* __restrict__ Gemb) {
    __shared__ short As[128][40];
    __shared__ short Bs[128][40];
    int f32 = *dflag;
    int n0 = blockIdx.x * 128;   // 16 tiles over 2048 gate-rows
    int m0 = blockIdx.y * 128;   // 32 tiles over 4096 hi/lo rows
    int tid = threadIdx.x, lane = tid & 63, wv = tid >> 6;
    int wm = wv >> 1, wn = wv & 1;
    f4v acc[16] = {};
    for (int k0 = 0; k0 < 512; k0 += 32) {
        for (int s = tid; s < 512; s += 256) {
            int r = s >> 2, cs = (s & 3) * 8;
            int R = m0 + r, e = R >> 1, part = R & 1;
            int b = e & 31, tt = e >> 5;
            size_t ei = (size_t)captions[b * L_ + tt] * H_ + k0 + cs;
            *(s8v*)&As[r][cs] = part ? ld8lo(embed, ei, f32) : ld8(embed, ei, f32);
        }
        for (int s = tid; s < 512; s += 256) {
            int r = s >> 2, cs = (s & 3) * 8;
            *(s8v*)&Bs[r][cs] = ld8(w_ih0, (size_t)(n0 + r) * 1024 + k0 + cs, f32);
        }
        __syncthreads();
        int kq = (lane >> 4) * 8;
        s8v af[4], bfv[4];
        for (int i = 0; i < 4; ++i) af[i]  = *(const s8v*)&As[wm * 64 + i * 16 + (lane & 15)][kq];
        for (int i = 0; i < 4; ++i) bfv[i] = *(const s8v*)&Bs[wn * 64 + i * 16 + (lane & 15)][kq];
        for (int mi = 0; mi < 4; ++mi)
            for (int ni = 0; ni < 4; ++ni)
                acc[mi * 4 + ni] = __builtin_amdgcn_mfma_f32_16x16x32_bf16(af[mi], bfv[ni], acc[mi * 4 + ni], 0, 0, 0);
        __syncthreads();
    }
    int n = lane & 15, quad = lane >> 4;
    for (int ni = 0; ni < 4; ++ni) {
        int col = n0 + wn * 64 + ni * 16 + n;
        for (int mi = 0; mi < 4; ++mi) {
            f4v a = acc[mi * 4 + ni];
            int rowbase = m0 + wm * 64 + mi * 16 + quad * 4;
            int e0 = rowbase >> 1;
            Gemb[(size_t)e0 * 2048 + col]       = a[0] + a[1];
            Gemb[(size_t)(e0 + 1) * 2048 + col] = a[2] + a[3];
        }
    }
}

// ---------------- feature MLP (unchanged from round 3) ----------------
__global__ __launch_bounds__(256) void k_feat1(const int* __restrict__ dflag,
                                               const void* __restrict__ feat,
                                               const void* __restrict__ w,
                                               const void* __restrict__ bias,
                                               float* __restrict__ t1) {
    int f32 = *dflag;
    int wid = (blockIdx.x * 256 + threadIdx.x) >> 6;
    int lane = threadIdx.x & 63;
    int b = wid >> 9, o = wid & 511;
    float acc = 0.f;
    for (int k = lane; k < INP; k += 64)
        acc += ldf(feat, (size_t)b * INP + k, f32) * ldf(w, (size_t)o * INP + k, f32);
    for (int off = 32; off; off >>= 1) acc += __shfl_down(acc, off, 64);
    if (lane == 0) {
        acc += ldf(bias, o, f32);
        t1[b * H_ + o] = acc > 0.f ? acc : 0.f;
    }
}

__global__ __launch_bounds__(256) void k_feat2(const int* __restrict__ dflag,
                                               const float* __restrict__ t1,
                                               const void* __restrict__ w,
                                               const void* __restrict__ bias,
                                               float* __restrict__ c0, float* __restrict__ c1,
                                               bf16* __restrict__ h0hi, bf16* __restrict__ h0lo,
                                               bf16* __restrict__ h1hi, bf16* __restrict__ h1lo) {
    int f32 = *dflag;
    int wid = (blockIdx.x * 256 + threadIdx.x) >> 6;
    int lane = threadIdx.x & 63;
    int b = wid >> 9, o = wid & 511;
    float acc = 0.f;
    for (int k = lane; k < H_; k += 64)
        acc += t1[b * H_ + k] * ldf(w, (size_t)o * H_ + k, f32);
    for (int off = 32; off; off >>= 1) acc += __shfl_down(acc, off, 64);
    if (lane == 0) {
        float v = acc + ldf(bias, o, f32);
        int idx = b * H_ + o;
        c0[idx] = v; c1[idx] = v;
        bf16 hi, lo; split_hl(v, hi, lo);
        h0hi[idx] = hi; h0lo[idx] = lo;
        h1hi[idx] = hi; h1lo[idx] = lo;
    }
}

// ---------------- persistent recurrence kernel: 64 steps of att->cell0->cell1 --------
__global__ __launch_bounds__(256, 1) void k_recur(
        const bf16* __restrict__ enc16,
        const bf16* __restrict__ Wp0, const bf16* __restrict__ Wp1,
        const float* __restrict__ bias0, const float* __restrict__ bias1,
        const float* __restrict__ Gemb,
        float* __restrict__ c0, float* __restrict__ c1,
        bf16* __restrict__ h0hiA, bf16* __restrict__ h0loA,
        bf16* __restrict__ h0hiB, bf16* __restrict__ h0loB,
        bf16* __restrict__ h1hiA, bf16* __restrict__ h1loA,
        bf16* __restrict__ h1hiB, bf16* __restrict__ h1loB,
        bf16* __restrict__ ctxhi, bf16* __restrict__ ctxlo,
        bf16* __restrict__ hs, int* __restrict__ bar) {
    __shared__ short Asm[64][136];
    __shared__ short Wsm[16][136];
    __shared__ float ep[4][4][32];
    __shared__ float qs[H_];
    __shared__ float sc[256];
    __shared__ float red[256];
    const float SCALE = 0.04419417382415922f;
    int blk = blockIdx.x, tid = threadIdx.x;
    int lane = tid & 63, wv = tid >> 6;
    int u0 = blk * 4;                 // 4 hidden units per block, 128 blocks = 512
    int nbar = 0;

    for (int t = 0; t < L_; ++t) {
        int p = t & 1;
        const bf16* h0hi_p = p ? h0hiB : h0hiA;  const bf16* h0lo_p = p ? h0loB : h0loA;
        bf16* h0hi_n = p ? h0hiA : h0hiB;        bf16* h0lo_n = p ? h0loA : h0loB;
        const bf16* h1hi_p = p ? h1hiB : h1hiA;  const bf16* h1lo_p = p ? h1loB : h1loA;
        bf16* h1hi_n = p ? h1hiA : h1hiB;        bf16* h1lo_n = p ? h1loA : h1loB;

        // ---- Phase A: attention (blocks 0..31, one batch each) ----
        if (blk < 32) {
            int b = blk;
            for (int i = tid; i < H_; i += 256)
                qs[i] = (float)h1hi_p[b * H_ + i] + (float)h1lo_p[b * H_ + i];
            __syncthreads();
            for (int tt = wv; tt < TENC; tt += 4) {
                size_t base = ((size_t)b * TENC + tt) * H_;
                float a = 0.f;
                for (int k = lane; k < H_; k += 64) a += qs[k] * (float)enc16[base + k];
                for (int off = 32; off; off >>= 1) a += __shfl_down(a, off, 64);
                if (lane == 0) sc[tt] = a * SCALE;
            }
            __syncthreads();
            red[tid] = (tid < TENC) ? sc[tid] : -1e30f;
            __syncthreads();
            for (int s = 128; s; s >>= 1) { if (tid < s) red[tid] = fmaxf(red[tid], red[tid + s]); __syncthreads(); }
            float m = red[0];
            __syncthreads();
            float e = (tid < TENC) ? expf(sc[tid] - m) : 0.f;
            red[tid] = e;
            __syncthreads();
            for (int s = 128; s; s >>= 1) { if (tid < s) red[tid] += red[tid + s]; __syncthreads(); }
            float inv = 1.0f / red[0];
            __syncthreads();
            if (tid < TENC) sc[tid] = e * inv;
            __syncthreads();
            int j0 = tid * 2;
            float a0 = 0.f, a1 = 0.f;
            for (int tt = 0; tt < TENC; ++tt) {
                size_t base = ((size_t)b * TENC + tt) * H_ + j0;
                float pr = sc[tt];
                a0 += pr * (float)enc16[base];
                a1 += pr * (float)enc16[base + 1];
            }
            bf16 hi, lo;
            split_hl(a0, hi, lo); ctxhi[b * H_ + j0] = hi; ctxlo[b * H_ + j0] = lo;
            split_hl(a1, hi, lo); ctxhi[b * H_ + j0 + 1] = hi; ctxlo[b * H_ + j0 + 1] = lo;
        }
        ++nbar; gridbar(bar, nbar * NBLK);

        // ---- Phase B: cell0 (A=[ctx;h0prev] hi/lo, K=1024; 16 W-rows/block) ----
        {
            f4v acc = {};
            for (int kc = 0; kc < 8; ++kc) {
                int kbase = kc * 128;
                for (int s = tid; s < 1024; s += 256) {
                    int r = s >> 4, cs = (s & 15) * 8;
                    int b = r >> 1, part = r & 1;
                    int k = kbase + cs;
                    const bf16* src;
                    if (k < 512) src = (part ? ctxlo : ctxhi) + b * H_ + k;
                    else         src = (part ? h0lo_p : h0hi_p) + b * H_ + (k - 512);
                    *(s8v*)&Asm[r][cs] = *(const s8v*)src;
                }
                {
                    int r = tid >> 4, cs = (tid & 15) * 8;
                    int gate = r >> 2, u = r & 3;
                    size_t j = (size_t)(gate * H_ + u0 + u);
                    *(s8v*)&Wsm[r][cs] = *(const s8v*)(Wp0 + j * 1024 + kbase + cs);
                }
                __syncthreads();
                int mrow = wv * 16 + (lane & 15);
                for (int kk = 0; kk < 4; ++kk) {
                    int kcol = kk * 32 + (lane >> 4) * 8;
                    s8v a  = *(const s8v*)&Asm[mrow][kcol];
                    s8v b0 = *(const s8v*)&Wsm[lane & 15][kcol];
                    acc = __builtin_amdgcn_mfma_f32_16x16x32_bf16(a, b0, acc, 0, 0, 0);
                }
                __syncthreads();
            }
            int n = lane & 15, quad = lane >> 4;
            int b0i = wv * 8 + quad * 2;
            ep[n >> 2][n & 3][b0i]     = acc[0] + acc[1];
            ep[n >> 2][n & 3][b0i + 1] = acc[2] + acc[3];
            __syncthreads();
            if (tid < 128) {
                int b = tid & 31, u = tid >> 5;
                int j = u0 + u;
                size_t e = (size_t)(t * 32 + b) * 2048;
                float gi = ep[0][u][b] + bias0[j]        + Gemb[e + j];
                float gf = ep[1][u][b] + bias0[512 + j]  + Gemb[e + 512 + j];
                float gg = ep[2][u][b] + bias0[1024 + j] + Gemb[e + 1024 + j];
                float go = ep[3][u][b] + bias0[1536 + j] + Gemb[e + 1536 + j];
                float c = c0[b * H_ + j];
                float c2 = sigf(gf) * c + sigf(gi) * tanhf(gg);
                float h2 = sigf(go) * tanhf(c2);
                c0[b * H_ + j] = c2;
                bf16 hi, lo; split_hl(h2, hi, lo);
                h0hi_n[b * H_ + j] = hi; h0lo_n[b * H_ + j] = lo;
            }
        }
        ++nbar; gridbar(bar, nbar * NBLK);

        // ---- Phase C: cell1 (A=[h0new;h1prev] hi/lo, K=1024) ----
        {
            f4v acc = {};
            for (int kc = 0; kc < 8; ++kc) {
                int kbase = kc * 128;
                for (int s = tid; s < 1024; s += 256) {
                    int r = s >> 4, cs = (s & 15) * 8;
                    int b = r >> 1, part = r & 1;
                    int k = kbase + cs;
                    const bf16* src;
                    if (k < 512) src = (part ? h0lo_n : h0hi_n) + b * H_ + k;
                    else         src = (part ? h1lo_p : h1hi_p) + b * H_ + (k - 512);
                    *(s8v*)&Asm[r][cs] = *(const s8v*)src;
                }
                {
                    int r = tid >> 4, cs = (tid & 15) * 8;
                    int gate = r >> 2, u = r & 3;
                    size_t j = (size_t)(gate * H_ + u0 + u);
                    *(s8v*)&Wsm[r][cs] = *(const s8v*)(Wp1 + j * 1024 + kbase + cs);
                }
                __syncthreads();
                int mrow = wv * 16 + (lane & 15);
                for (int kk = 0; kk < 4; ++kk) {
                    int kcol = kk * 32 + (lane >> 4) * 8;
                    s8v a  = *(const s8v*)&Asm[mrow][kcol];
                    s8v b0 = *(const s8v*)&Wsm[lane & 15][kcol];
                    acc = __builtin_amdgcn_mfma_f32_16x16x32_bf16(a, b0, acc, 0, 0, 0);
                }
                __syncthreads();
            }
            int n = lane & 15, quad = lane >> 4;
            int b0i = wv * 8 + quad * 2;
            ep[n >> 2][n & 3][b0i]     = acc[0] + acc[1];
            ep[n >> 2][n & 3][b0i + 1] = acc[2] + acc[3];
            __syncthreads();
            if (tid < 128) {
                int b = tid & 31, u = tid >> 5;
                int j = u0 + u;
                float gi = ep[0][u][b] + bias1[j];
                float gf = ep[1][u][b] + bias1[512 + j];
                float gg = ep[2][u][b] + bias1[1024 + j];
                float go = ep[3][u][b] + bias1[1536 + j];
                float c = c1[b * H_ + j];
                float c2 = sigf(gf) * c + sigf(gi) * tanhf(gg);
                float h2 = sigf(go) * tanhf(c2);
                c1[b * H_ + j] = c2;
                bf16 hi, lo; split_hl(h2, hi, lo);
                h1hi_n[b * H_ + j] = hi; h1lo_n[b * H_ + j] = lo;
                hs[(size_t)(t * 32 + b) * H_ + j] = hi;
            }
        }
        ++nbar; gridbar(bar, nbar * NBLK);
    }
}

// ---------------- vocab projection (grid transposed: m fastest for fcw reuse) -------
__global__ __launch_bounds__(256) void k_vocab(const int* __restrict__ dflag,
                                               const bf16* __restrict__ hs,
                                               const void* __restrict__ fcw,
                                               const void* __restrict__ fcb,
                                               void* __restrict__ out) {
    __shared__ short As[128][40];
    __shared__ short Bs[128][40];
    int f32 = *dflag;
    int m0 = blockIdx.x * 128;      // 16 (fast-varying: co-temporal fcw sharers)
    int n0 = blockIdx.y * 128;      // 250
    int tid = threadIdx.x, lane = tid & 63, wv = tid >> 6;
    int wm = wv >> 1, wn = wv & 1;
    f4v acc[16] = {};
    for (int k0 = 0; k0 < 512; k0 += 32) {
        for (int s = tid; s < 512; s += 256) {
            int r = s >> 2, cs = (s & 3) * 8;
            *(s8v*)&As[r][cs] = *(const s8v*)(hs + (size_t)(m0 + r) * 512 + k0 + cs);
        }
        for (int s = tid; s < 512; s += 256) {
            int r = s >> 2, cs = (s & 3) * 8;
            *(s8v*)&Bs[r][cs] = ld8(fcw, (size_t)(n0 + r) * 512 + k0 + cs, f32);
        }
        __syncthreads();
        int kq = (lane >> 4) * 8;
        s8v af[4], bfv[4];
        for (int i = 0; i < 4; ++i) af[i]  = *(const s8v*)&As[wm * 64 + i * 16 + (lane & 15)][kq];
        for (int i = 0; i < 4; ++i) bfv[i] = *(const s8v*)&Bs[wn * 64 + i * 16 + (lane & 15)][kq];
        for (int mi = 0; mi < 4; ++mi)
            for (int ni = 0; ni < 4; ++ni)
                acc[mi * 4 + ni] = __builtin_amdgcn_mfma_f32_16x16x32_bf16(af[mi], bfv[ni], acc[mi * 4 + ni], 0, 0, 0);
        __syncthreads();
    }
    int n = lane & 15, quad = lane >> 4;
    for (int ni = 0; ni < 4; ++ni) {
        int col = n0 + wn * 64 + ni * 16 + n;
        float bias = ldf(fcb, col, f32);
        for (int mi = 0; mi < 4; ++mi) {
            f4v a = acc[mi * 4 + ni];
            for (int rg = 0; rg < 4; ++rg) {
                int row = m0 + wm * 64 + mi * 16 + quad * 4 + rg;
                float v = a[rg] + bias;
                if (f32) ((float*)out)[(size_t)row * V_ + col] = v;
                else     ((bf16*)out)[(size_t)row * V_ + col] = (bf16)v;
            }
        }
    }
}

extern "C" void kernel_launch(void* const* d_in, const int* in_sizes, int n_in,
                              void* d_out, int out_size, void* d_ws, size_t ws_size,
                              hipStream_t stream) {
    const void* features = d_in[0];
    const int*  captions = (const int*)d_in[1];
    const void* enc      = d_in[3];
    const void* embed    = d_in[4];
    const void* ft1w     = d_in[5];
    const void* ft1b     = d_in[6];
    const void* ft2w     = d_in[7];
    const void* ft2b     = d_in[8];
    const void* w_ih0    = d_in[9];
    const void* w_hh0    = d_in[10];
    const void* b_ih0    = d_in[11];
    const void* b_hh0    = d_in[12];
    const void* w_ih1    = d_in[13];
    const void* w_hh1    = d_in[14];
    const void* b_ih1    = d_in[15];
    const void* b_hh1    = d_in[16];
    const void* fcw      = d_in[17];
    const void* fcb      = d_in[18];

    char* ws = (char*)d_ws;
    size_t off = 0;
    float* t1    = (float*)(ws + off); off += 32 * 512 * 4;
    float* c0    = (float*)(ws + off); off += 32 * 512 * 4;
    float* c1    = (float*)(ws + off); off += 32 * 512 * 4;
    bf16* h0hiA  = (bf16*)(ws + off); off += 32 * 512 * 2;
    bf16* h0loA  = (bf16*)(ws + off); off += 32 * 512 * 2;
    bf16* h0hiB  = (bf16*)(ws + off); off += 32 * 512 * 2;
    bf16* h0loB  = (bf16*)(ws + off); off += 32 * 512 * 2;
    bf16* h1hiA  = (bf16*)(ws + off); off += 32 * 512 * 2;
    bf16* h1loA  = (bf16*)(ws + off); off += 32 * 512 * 2;
    bf16* h1hiB  = (bf16*)(ws + off); off += 32 * 512 * 2;
    bf16* h1loB  = (bf16*)(ws + off); off += 32 * 512 * 2;
    bf16* ctxhi  = (bf16*)(ws + off); off += 32 * 512 * 2;
    bf16* ctxlo  = (bf16*)(ws + off); off += 32 * 512 * 2;
    bf16* hs     = (bf16*)(ws + off); off += (size_t)2048 * 512 * 2;
    bf16* enc16  = (bf16*)(ws + off); off += (size_t)32 * 196 * 512 * 2;
    bf16* Wp0    = (bf16*)(ws + off); off += (size_t)2048 * 1024 * 2;
    bf16* Wp1    = (bf16*)(ws + off); off += (size_t)2048 * 1024 * 2;
    float* bias0 = (float*)(ws + off); off += 2048 * 4;
    float* bias1 = (float*)(ws + off); off += 2048 * 4;
    float* Gemb  = (float*)(ws + off); off += (size_t)2048 * 2048 * 4;
    int* dflag   = (int*)(ws + off); off += 16;
    int* bar     = (int*)(ws + off); off += 16;

    k_detect<<<1, 256, 0, stream>>>(features, dflag);
    k_prep<<<1024, 256, 0, stream>>>(dflag, enc, w_ih0, w_hh0, w_ih1, w_hh1,
                                     b_ih0, b_hh0, b_ih1, b_hh1,
                                     enc16, Wp0, Wp1, bias0, bias1, bar);
    k_gemb<<<dim3(16, 32), 256, 0, stream>>>(dflag, captions, embed, w_ih0, Gemb);
    k_feat1<<<4096, 256, 0, stream>>>(dflag, features, ft1w, ft1b, t1);
    k_feat2<<<4096, 256, 0, stream>>>(dflag, t1, ft2w, ft2b, c0, c1,
                                      h0hiA, h0loA, h1hiA, h1loA);
    k_recur<<<NBLK, 256, 0, stream>>>(enc16, Wp0, Wp1, bias0, bias1, Gemb,
                                      c0, c1,
                                      h0hiA, h0loA, h0hiB, h0loB,
                                      h1hiA, h1loA, h1hiB, h1loB,
                                      ctxhi, ctxlo, hs, bar);
    k_vocab<<<dim3(16, 250), 256, 0, stream>>>(dflag, hs, fcw, fcb, (void*)d_out);
}